// Round 8
// baseline (25.063 us; speedup 1.0000x reference)
//
#include <hip/hip_runtime.h>

// TransientGenerator — gather with zero-padded templates + scalarized meta.
// Prep kernel writes [1024 zeros | row | 1024 zeros] per template into d_ws,
// so the gather inner loop needs NO bounds checks (pad absorbs all offsets
// reachable from the ballot interval) and NO per-lane address math
// (uniform SGPR base via readfirstlane + fixed v_tid offset + imm k*1024).

constexpr int SR    = 16000;  // SAMPLE_RATE
constexpr int TL    = 1600;   // TRANSIENT_SAMPLES
constexpr int MAXT  = 256;    // MAX_TRANSIENTS (== blockDim)
constexpr int NTHR  = 256;
constexpr int CHUNK = 1024;   // NTHR * 4 samples per block
constexpr int PAD   = 1024;   // covers o in (-CHUNK, TL+1023]
constexpr int ROWP  = PAD + TL + PAD;   // 3648 floats per padded row

__global__ __launch_bounds__(256)
void pad_templates(const float* __restrict__ templates, float* __restrict__ tpad, int n_tr)
{
    const int total = n_tr * ROWP;
    for (int i = blockIdx.x * blockDim.x + threadIdx.x; i < total;
         i += gridDim.x * blockDim.x) {
        const int r = i / ROWP;
        const int t = (i - r * ROWP) - PAD;
        tpad[i] = ((unsigned)t < (unsigned)TL) ? templates[r * TL + t] : 0.0f;
    }
}

__global__ __launch_bounds__(NTHR)
void transient_gather(const float* __restrict__ timings,   // [B,T]
                      const int*   __restrict__ ids,       // [B,T]
                      const float* __restrict__ gains,     // [B,T]
                      const float* __restrict__ tpad,      // [n_tr,ROWP] zero-padded
                      float*       __restrict__ out,       // [B,A]
                      int T, int n_tr, int A)
{
    __shared__ int2               s_m[MAXT];
    __shared__ unsigned long long s_mask[NTHR / 64];

    const int b      = blockIdx.y;
    const int chunk0 = blockIdx.x * CHUNK;
    const int tid    = (int)threadIdx.x;

    {   // stage transient j = tid (T == NTHR); ballot the overlap interval
        const float tm = timings[(size_t)b * T + tid];
        const float g  = gains  [(size_t)b * T + tid];
        const int   id = ids    [(size_t)b * T + tid];
        const int   ts = (int)floorf(tm * (float)SR);   // matches jnp.floor(t*SR) fp32
        const bool ok  = (g > 0.0f) & (id < n_tr) & (ts < A);
        const int tsc  = min(max(ts, 0), A);            // clamp preserves sorted order
        const int idc  = min(max(id, 0), n_tr - 1);
        s_m[tid] = make_int2((tsc << 8) | idc, ok ? __float_as_int(g) : 0);
        const bool ov = (tsc < chunk0 + CHUNK) && (tsc + TL > chunk0);
        const unsigned long long mball = __ballot(ov);
        if ((tid & 63) == 0) s_mask[tid >> 6] = mball;
    }
    __syncthreads();

    int lo = T, hi = -1;
#pragma unroll
    for (int w = 0; w < NTHR / 64; ++w) {
        const unsigned long long mw = s_mask[w];
        if (mw) {
            lo = min(lo, w * 64 + (int)__builtin_ctzll(mw));
            hi = max(hi, w * 64 + 63 - (int)__builtin_clzll(mw));
        }
    }

    float acc[4] = {0.f, 0.f, 0.f, 0.f};

    for (int j = lo; j <= hi; ++j) {
        const int2 mj = s_m[j];
        const int  mx  = __builtin_amdgcn_readfirstlane(mj.x);   // uniform -> SGPR
        const int  mgb = __builtin_amdgcn_readfirstlane(mj.y);
        if (mgb == 0) continue;                                  // uniform skip (invalid)
        const float g  = __int_as_float(mgb);
        const int   ts = mx >> 8;
        // uniform padded-row pointer; all offsets tid + k*256 are in-row by construction:
        // ts in (chunk0-TL, chunk0+CHUNK) => chunk0 - ts + tid + k*256 in (-1024, 2624)
        const float* __restrict__ p =
            tpad + (size_t)(mx & 255) * ROWP + PAD + (chunk0 - ts);
#pragma unroll
        for (int k = 0; k < 4; ++k)
            acc[k] = fmaf(g, p[tid + k * NTHR], acc[k]);         // no masks, imm offsets
    }

    float* ob = out + (size_t)b * A + chunk0 + tid;
#pragma unroll
    for (int k = 0; k < 4; ++k) {
        if (chunk0 + tid + k * NTHR < A)
            __builtin_nontemporal_store(acc[k], &ob[k * NTHR]);  // NT: keep L2 for templates
    }
}

// Fallback (proven R7 kernel) if ws is too small for the padded templates.
__global__ __launch_bounds__(NTHR)
void transient_gather_guard(const float* __restrict__ timings, const int* __restrict__ ids,
                            const float* __restrict__ gains, const float* __restrict__ templates,
                            float* __restrict__ out, int T, int n_tr, int A)
{
    __shared__ int2               s_m[MAXT];
    __shared__ unsigned long long s_mask[NTHR / 64];
    const int b = blockIdx.y, chunk0 = blockIdx.x * CHUNK, tid = (int)threadIdx.x;
    {
        const float tm = timings[(size_t)b * T + tid];
        const float g  = gains  [(size_t)b * T + tid];
        const int   id = ids    [(size_t)b * T + tid];
        const int   ts = (int)floorf(tm * (float)SR);
        const bool ok  = (g > 0.0f) & (id < n_tr) & (ts < A);
        const int tsc  = min(max(ts, 0), A);
        const int idc  = min(max(id, 0), n_tr - 1);
        s_m[tid] = make_int2((tsc << 8) | idc, ok ? __float_as_int(g) : 0);
        const bool ov = (tsc < chunk0 + CHUNK) && (tsc + TL > chunk0);
        const unsigned long long mball = __ballot(ov);
        if ((tid & 63) == 0) s_mask[tid >> 6] = mball;
    }
    __syncthreads();
    int lo = T, hi = -1;
#pragma unroll
    for (int w = 0; w < NTHR / 64; ++w) {
        const unsigned long long mw = s_mask[w];
        if (mw) {
            lo = min(lo, w * 64 + (int)__builtin_ctzll(mw));
            hi = max(hi, w * 64 + 63 - (int)__builtin_clzll(mw));
        }
    }
    float acc[4] = {0.f, 0.f, 0.f, 0.f};
    const int off_base = chunk0 + tid;
    for (int j = lo; j <= hi; ++j) {
        const int2 m = s_m[j];
        const int ts = m.x >> 8;
        const float g = __int_as_float(m.y);
        const float* __restrict__ row = templates + (size_t)(m.x & 255) * TL;
        const int off0 = off_base - ts;
#pragma unroll
        for (int k = 0; k < 4; ++k) {
            const int o = off0 + k * NTHR;
            if ((unsigned)o < (unsigned)TL) acc[k] += g * row[o];
        }
    }
    float* ob = out + (size_t)b * A + off_base;
#pragma unroll
    for (int k = 0; k < 4; ++k)
        if (off_base + k * NTHR < A) __builtin_nontemporal_store(acc[k], &ob[k * NTHR]);
}

extern "C" void kernel_launch(void* const* d_in, const int* in_sizes, int n_in,
                              void* d_out, int out_size, void* d_ws, size_t ws_size,
                              hipStream_t stream) {
    const float* timings   = (const float*)d_in[0];
    const int*   ids       = (const int*)  d_in[1];
    const float* gains     = (const float*)d_in[2];
    const float* templates = (const float*)d_in[3];
    float*       out       = (float*)d_out;

    const int T    = MAXT;                 // reference MAX_TRANSIENTS
    const int B    = in_sizes[0] / T;
    const int n_tr = in_sizes[3] / TL;     // templates are [n_tr, TL]
    const int A    = out_size / B;         // audio_length

    dim3 grid((A + CHUNK - 1) / CHUNK, B), block(NTHR);
    const size_t need = (size_t)n_tr * ROWP * sizeof(float);
    if (ws_size >= need) {
        float* tpad = (float*)d_ws;
        pad_templates<<<dim3(80), dim3(256), 0, stream>>>(templates, tpad, n_tr);
        transient_gather<<<grid, block, 0, stream>>>(timings, ids, gains, tpad, out,
                                                     T, n_tr, A);
    } else {
        transient_gather_guard<<<grid, block, 0, stream>>>(timings, ids, gains, templates,
                                                           out, T, n_tr, A);
    }
}